// Round 8
// baseline (2175.400 us; speedup 1.0000x reference)
//
#include <hip/hip_runtime.h>
#include <stdint.h>

#define NN 50000
#define DEG 16
#define MT 32
#define NBLK ((NN + MT - 1) / MT)
#define LOG2E 1.4426950408889634f

typedef short bf16x8 __attribute__((ext_vector_type(8)));
typedef float f32x4 __attribute__((ext_vector_type(4)));
typedef unsigned short u16;
typedef unsigned int u32;

static __device__ __forceinline__ u16 f2bf(float f) {
  union { float f; u32 u; } v; v.f = f;
  u32 u = v.u + 0x7FFFu + ((v.u >> 16) & 1u);   // round-to-nearest-even
  return (u16)(u >> 16);
}
static __device__ __forceinline__ float rcp_(float x) {
  return __builtin_amdgcn_rcpf(x);
}
static __device__ __forceinline__ float ex2_(float x) {
  return __builtin_amdgcn_exp2f(x);
}
static __device__ __forceinline__ void gload_lds16(const void* g, void* l) {
  __builtin_amdgcn_global_load_lds(
      (const __attribute__((address_space(1))) void*)g,
      (__attribute__((address_space(3))) void*)l, 16, 0, 0);
}

// ---------------------------------------------------------------------------
// Prep. v8 gate-weight layout: 16 waves, wave w owns units u=8w..8w+7, all 4
// gates, packed as 2 ntiles of 16 cols: nt0=[i(u0..7)|f(u0..7)],
// nt1=[g|o]. Col (w,nt,lane): u=8w+(lane&7), G=nt*2+((lane>>3)&1).
// Gates i,f,o are scaled by -log2e (NEGATED: sigmoid needs exp(-x), so the
// negate is folded into the weights, exactly); g by +2*log2e.
//   wpk[(((w*2+nt)*8+kt)*64+lane)*8+j] = sc(G)*W[G*128+u][k],
//   k = kt*32+(lane>>4)*8+j,  W = [w_ih | w_hh] along K.
// ---------------------------------------------------------------------------
__global__ void k_prep(const float* __restrict__ x, u16* __restrict__ xb,
                       const float* __restrict__ wih1, const float* __restrict__ whh1, u16* __restrict__ wpk1,
                       const float* __restrict__ wih2, const float* __restrict__ whh2, u16* __restrict__ wpk2,
                       const float* __restrict__ lr1, const float* __restrict__ ll1, u16* __restrict__ epk1,
                       const float* __restrict__ lr2, const float* __restrict__ ll2, u16* __restrict__ epk2,
                       const float* __restrict__ linw, u16* __restrict__ hpk,
                       const float* __restrict__ bi1, const float* __restrict__ bh1, float* __restrict__ bs1,
                       const float* __restrict__ bi2, const float* __restrict__ bh2, float* __restrict__ bs2) {
  int b = blockIdx.x;
  if (b < 128) {
    const float* wih = (b < 64) ? wih1 : wih2;
    const float* whh = (b < 64) ? whh1 : whh2;
    u16* wpk = (b < 64) ? wpk1 : wpk2;
    int t = (b & 63) * 256 + threadIdx.x;          // 0..16383
    int lane = t & 63, kt = (t >> 6) & 7, nt = (t >> 9) & 1, w = (t >> 10) & 15;
    int u = 8 * w + (lane & 7);
    int G = nt * 2 + ((lane >> 3) & 1);
    int col = G * 128 + u;
    int k0 = kt * 32 + (lane >> 4) * 8;
    float sc = (G == 2) ? 2.f * LOG2E : -LOG2E;
#pragma unroll
    for (int j = 0; j < 8; ++j) {
      int k = k0 + j;
      float v = (k < 128) ? wih[col * 128 + k] : whh[col * 128 + k - 128];
      wpk[t * 8 + j] = f2bf(sc * v);
    }
  } else if (b < 160) {
    // epilogue weights (8-wave layout): k<128 lin_r(x), k>=128 lin_l(h)
    const float* lrw = (b < 144) ? lr1 : lr2;
    const float* llw = (b < 144) ? ll1 : ll2;
    u16* epk = (b < 144) ? epk1 : epk2;
    int t = ((b - 128) & 15) * 256 + threadIdx.x;  // 0..4095
    int lane = t & 63, kt = (t >> 6) & 7, w = (t >> 9) & 7;
    int col = w * 16 + (lane & 15);
    int k0 = kt * 32 + (lane >> 4) * 8;
#pragma unroll
    for (int j = 0; j < 8; ++j) {
      int k = k0 + j;
      epk[t * 8 + j] = f2bf(k < 128 ? lrw[col * 128 + k] : llw[col * 128 + k - 128]);
    }
  } else if (b < 164) {
    // head weights [64,128], waves 0..3 — unscaled
    int t = (b - 160) * 256 + threadIdx.x;         // 0..1023
    int lane = t & 63, kt = (t >> 6) & 3, w = (t >> 8) & 3;
    int col = w * 16 + (lane & 15);
    int k0 = kt * 32 + (lane >> 4) * 8;
#pragma unroll
    for (int j = 0; j < 8; ++j) hpk[t * 8 + j] = f2bf(linw[col * 128 + k0 + j]);
  } else if (b < 168) {
    int t = (b - 164) * 256 + threadIdx.x;         // 0..1023
    if (t < 1024) {
      int i = t & 511;
      float sc = ((i >> 7) == 2) ? 2.f * LOG2E : -LOG2E;
      if (t < 512) bs1[i] = sc * (bi1[i] + bh1[i]);
      else bs2[i] = sc * (bi2[i] + bh2[i]);
    }
  } else {
    int i = (b - 168) * 256 + threadIdx.x;
    int stride = (gridDim.x - 168) * 256;
    for (; i < NN * 128 / 4; i += stride) {
      float4 v = ((const float4*)x)[i];
      ushort4 o;
      o.x = f2bf(v.x); o.y = f2bf(v.y); o.z = f2bf(v.z); o.w = f2bf(v.w);
      ((ushort4*)xb)[i] = o;
    }
  }
}

// ---------------------------------------------------------------------------
// Fused SAGE-LSTM layer, v8: 1024 threads = 16 waves, MT=32 nodes/block,
// 2 blocks/CU (launch_bounds(1024,8): 8 waves/SIMD).
// Wave owns 8 hidden units x 4 gates (packed cols): wreg = 64 VGPR (half of
// v7) -> doubled occupancy; EW of one wave overlaps MFMA of others.
// Gate exchange is in-register: lanes l and l^8 hold complementary gates for
// the same unit/rows; one __shfl_xor(.,8) x 8 f32 swaps them; rows split
// lo/hi-lane so all 64 lanes do 4 EW elems. i,f,o in NEGATED exp2 domain
// (weights pre-negated, bit-exact). One counted barrier per step (v7 CBAR).
// LDS XOR-swizzle: byte ^= (row&15)<<4.
// ---------------------------------------------------------------------------

#define GATHER(DCODE, PDST)                                                   \
  do {                                                                        \
    int idx_;                                                                 \
    if ((DCODE) < DEG) idx_ = IDX[grow * DEG + (DCODE)];                      \
    else idx_ = (node0 + grow < NN) ? node0 + grow : NN - 1;                  \
    const char* gsw_ = (const char*)(xin + (size_t)idx_ * 128) +              \
                       ((lr * 16) ^ ((grow & 15) << 4));                      \
    gload_lds16(gsw_, (PDST) + (w * 4) * 128);                                \
  } while (0)

#define CBAR(N)                                                               \
  do {                                                                        \
    asm volatile("s_waitcnt vmcnt(" #N ") lgkmcnt(0)" ::: "memory");          \
    __builtin_amdgcn_s_barrier();                                             \
    __builtin_amdgcn_sched_barrier(0);                                        \
  } while (0)

template <int L2>
__global__ __launch_bounds__(1024, 8) void k_layer(
    const u16* __restrict__ xin, const int* __restrict__ src,
    const u16* __restrict__ wpk, const float* __restrict__ bsum,
    const u16* __restrict__ epk, const float* __restrict__ linlb,
    u16* __restrict__ hout, const u16* __restrict__ hpk,
    const float* __restrict__ linb, float* __restrict__ dout) {
  __shared__ __align__(16) u16 AX[3][MT * 128];   // 3 x 8 KB (triple buffer)
  __shared__ __align__(16) u16 AH[2][MT * 128];   // 2 x 8 KB
  __shared__ int IDX[MT * DEG];                   // 2 KB

  const int tid = threadIdx.x;
  const int w = tid >> 6, l = tid & 63;
  const int lr = l & 15, lh = l >> 4;
  const int node0 = blockIdx.x * MT;
  const int grow = (w & 7) * 4 + lh;  // gather row (waves 0..7 only)

  // ---- register-resident weight panel: 16 frags = 64 VGPRs ----
  bf16x8 wreg[2][8];
#pragma unroll
  for (int nt = 0; nt < 2; ++nt)
#pragma unroll
    for (int kt = 0; kt < 8; ++kt)
      wreg[nt][kt] = *(const bf16x8*)(wpk + (size_t)(((w * 2 + nt) * 8 + kt) * 64 + l) * 8);

  if (tid < MT * DEG)
    IDX[tid] = (node0 + (tid >> 4) < NN) ? src[node0 * DEG + tid] : 0;

  const int uu = 8 * w + (l & 7);     // this lane's hidden unit
  const bool hi = (l & 8) != 0;       // col>=8 half: owns f,o; rows mt1
  float gb[2];
#pragma unroll
  for (int nt = 0; nt < 2; ++nt)
    gb[nt] = bsum[(nt * 2 + (hi ? 1 : 0)) * 128 + uu];
  __syncthreads();  // IDX ready; vmcnt drained

  // prologue: gather x_0 -> AX[0], x_1 -> AX[1] (waves 0..7)
  if (w < 8) {
    GATHER(0, AX[0]);
    GATHER(1, AX[1]);
  }

  f32x4 c4 = (f32x4){0.f, 0.f, 0.f, 0.f};
  CBAR(1);  // x_0 landed; x_1 still in flight

  u16 *pA = AX[0], *pB = AX[1], *pC = AX[2];

#pragma unroll 1
  for (int step = 0; step < DEG; ++step) {
    const int cb = step & 1, nb = cb ^ 1;

    // issue gather(step+2) into the free buffer (d=16 -> own features)
    if (w < 8 && step < DEG - 1) GATHER(step + 2, pC);

    // acc init = gate bias (pre-scaled/negated): free bias via MFMA C-in
    f32x4 acc[2][2];  // [mt][nt]
#pragma unroll
    for (int mt = 0; mt < 2; ++mt)
#pragma unroll
      for (int nt = 0; nt < 2; ++nt)
        acc[mt][nt] = (f32x4){gb[nt], gb[nt], gb[nt], gb[nt]};

    // x-part: K tiles 0..3
#pragma unroll
    for (int kt = 0; kt < 4; ++kt) {
      bf16x8 af[2];
#pragma unroll
      for (int mt = 0; mt < 2; ++mt) {
        int row = mt * 16 + lr;
        af[mt] = *(const bf16x8*)((const char*)pA + row * 256 +
                                  ((kt * 64 + lh * 16) ^ ((row & 15) << 4)));
      }
#pragma unroll
      for (int nt = 0; nt < 2; ++nt)
#pragma unroll
        for (int mt = 0; mt < 2; ++mt)
          acc[mt][nt] = __builtin_amdgcn_mfma_f32_16x16x32_bf16(af[mt], wreg[nt][kt], acc[mt][nt], 0, 0, 0);
    }

    // h-part: K tiles 4..7 (h == 0 at step 0)
    if (step) {
#pragma unroll
      for (int kt = 0; kt < 4; ++kt) {
        bf16x8 af[2];
#pragma unroll
        for (int mt = 0; mt < 2; ++mt) {
          int row = mt * 16 + lr;
          af[mt] = *(const bf16x8*)((const char*)AH[cb] + row * 256 +
                                    ((kt * 64 + lh * 16) ^ ((row & 15) << 4)));
        }
#pragma unroll
        for (int nt = 0; nt < 2; ++nt)
#pragma unroll
          for (int mt = 0; mt < 2; ++mt)
            acc[mt][nt] = __builtin_amdgcn_mfma_f32_16x16x32_bf16(af[mt], wreg[nt][4 + kt], acc[mt][nt], 0, 0, 0);
      }
    }

    // in-register gate exchange: lane l <-> l^8 (same unit, complementary
    // gates). lo sends its mt1 (i,g), hi sends its mt0 (f,o).
    f32x4 recv[2];
#pragma unroll
    for (int nt = 0; nt < 2; ++nt)
#pragma unroll
      for (int j = 0; j < 4; ++j) {
        float send = hi ? acc[0][nt][j] : acc[1][nt][j];
        recv[nt][j] = __shfl_xor(send, 8, 64);
      }

    // EW: lo lanes do rows mt0, hi lanes rows mt1; 4 elems each, no LDS.
    // i,f,o preacts are NEGATED (sigma(x) = rcp(1+ex2(nx))).
    const int rbase = (hi ? 16 : 0) + lh * 4;
#pragma unroll
    for (int j = 0; j < 4; ++j) {
      float ai = hi ? recv[0][j] : acc[0][0][j];
      float afv = hi ? acc[1][0][j] : recv[0][j];
      float ag = hi ? recv[1][j] : acc[0][1][j];
      float ao = hi ? acc[1][1][j] : recv[1][j];
      float iv = rcp_(1.f + ex2_(ai));
      float fv = rcp_(1.f + ex2_(afv));
      float gv = 1.f - 2.f * rcp_(1.f + ex2_(ag));
      float ov = rcp_(1.f + ex2_(ao));
      float cv = fv * c4[j] + iv * gv;
      c4[j] = cv;
      float th = 1.f - 2.f * rcp_(1.f + ex2_(2.f * LOG2E * cv));
      int row = rbase + j;
      *(u16*)((char*)AH[nb] + row * 256 + ((2 * uu) ^ ((row & 15) << 4))) =
          f2bf(ov * th);
    }

    // counted barrier: drain gather(step+1) only; keep gather(step+2) flying
    if (step < DEG - 1) CBAR(1);
    else CBAR(0);  // last step: drain the own-x gather for the epilogue

    u16* t_ = pA; pA = pB; pB = t_;
    t_ = pB; pB = pC; pC = t_;  // rotate: pA<-pB, pB<-pC, pC<-old pA
  }

  // Epilogue: out = lin_r(x_own) + lin_l(h_final) + b, ReLU. Waves 0..7
  // (v7 layout: wave w' owns out-cols [16w',16w'+16)). pA = own x; AH[0] = h.
  if constexpr (!L2) {
    if (w < 8) {
      float eb = linlb[w * 16 + lr];
      f32x4 eacc[2];
      eacc[0] = (f32x4){eb, eb, eb, eb};
      eacc[1] = (f32x4){eb, eb, eb, eb};
#pragma unroll
      for (int kt = 0; kt < 8; ++kt) {
        const u16* srcb = (kt < 4) ? pA : AH[0];
        int kb = (kt & 3) * 64 + lh * 16;
        bf16x8 af[2];
#pragma unroll
        for (int mt = 0; mt < 2; ++mt) {
          int row = mt * 16 + lr;
          af[mt] = *(const bf16x8*)((const char*)srcb + row * 256 +
                                    (kb ^ ((row & 15) << 4)));
        }
        bf16x8 bf = *(const bf16x8*)(epk + (size_t)((w * 8 + kt) * 64 + l) * 8);
#pragma unroll
        for (int mt = 0; mt < 2; ++mt)
          eacc[mt] = __builtin_amdgcn_mfma_f32_16x16x32_bf16(af[mt], bf, eacc[mt], 0, 0, 0);
      }
#pragma unroll
      for (int mt = 0; mt < 2; ++mt)
#pragma unroll
        for (int r = 0; r < 4; ++r) {
          int node = node0 + mt * 16 + lh * 4 + r;
          if (node < NN) {
            float v = fmaxf(eacc[mt][r], 0.f);
            hout[(size_t)node * 128 + w * 16 + lr] = f2bf(v);
          }
        }
    }
  } else {
    if (w < 8) {
      float eb = linlb[w * 16 + lr];
      f32x4 eacc[2];
      eacc[0] = (f32x4){eb, eb, eb, eb};
      eacc[1] = (f32x4){eb, eb, eb, eb};
#pragma unroll
      for (int kt = 0; kt < 8; ++kt) {
        const u16* srcb = (kt < 4) ? pA : AH[0];
        int kb = (kt & 3) * 64 + lh * 16;
        bf16x8 af[2];
#pragma unroll
        for (int mt = 0; mt < 2; ++mt) {
          int row = mt * 16 + lr;
          af[mt] = *(const bf16x8*)((const char*)srcb + row * 256 +
                                    (kb ^ ((row & 15) << 4)));
        }
        bf16x8 bf = *(const bf16x8*)(epk + (size_t)((w * 8 + kt) * 64 + l) * 8);
#pragma unroll
        for (int mt = 0; mt < 2; ++mt)
          eacc[mt] = __builtin_amdgcn_mfma_f32_16x16x32_bf16(af[mt], bf, eacc[mt], 0, 0, 0);
      }
      // stash relu(h2) into AH[1]
#pragma unroll
      for (int mt = 0; mt < 2; ++mt)
#pragma unroll
        for (int r = 0; r < 4; ++r) {
          int row = mt * 16 + lh * 4 + r;
          float v = fmaxf(eacc[mt][r], 0.f);
          int jj = 2 * (w * 16 + lr);
          *(u16*)((char*)AH[1] + row * 256 + (jj ^ ((row & 15) << 4))) = f2bf(v);
        }
    }
    __syncthreads();
    if (w < 4) {
      float hb = linb[w * 16 + lr];
      f32x4 hacc[2];
      hacc[0] = (f32x4){hb, hb, hb, hb};
      hacc[1] = (f32x4){hb, hb, hb, hb};
#pragma unroll
      for (int kt = 0; kt < 4; ++kt) {
        bf16x8 af[2];
#pragma unroll
        for (int mt = 0; mt < 2; ++mt) {
          int row = mt * 16 + lr;
          af[mt] = *(const bf16x8*)((const char*)AH[1] + row * 256 +
                                    ((kt * 64 + lh * 16) ^ ((row & 15) << 4)));
        }
        bf16x8 bf = *(const bf16x8*)(hpk + (size_t)((w * 4 + kt) * 64 + l) * 8);
#pragma unroll
        for (int mt = 0; mt < 2; ++mt)
          hacc[mt] = __builtin_amdgcn_mfma_f32_16x16x32_bf16(af[mt], bf, hacc[mt], 0, 0, 0);
      }
#pragma unroll
      for (int mt = 0; mt < 2; ++mt)
#pragma unroll
        for (int r = 0; r < 4; ++r) {
          int node = node0 + mt * 16 + lh * 4 + r;
          if (node < NN) dout[(size_t)node * 64 + w * 16 + lr] = hacc[mt][r];
        }
    }
  }
}

extern "C" void kernel_launch(void* const* d_in, const int* in_sizes, int n_in,
                              void* d_out, int out_size, void* d_ws, size_t ws_size,
                              hipStream_t stream) {
  const float* x    = (const float*)d_in[0];
  const int*   edge = (const int*)d_in[1];   // src = first N*DEG entries
  const float* wih1 = (const float*)d_in[2];
  const float* whh1 = (const float*)d_in[3];
  const float* bih1 = (const float*)d_in[4];
  const float* bhh1 = (const float*)d_in[5];
  const float* ll1w = (const float*)d_in[6];
  const float* ll1b = (const float*)d_in[7];
  const float* lr1w = (const float*)d_in[8];
  const float* wih2 = (const float*)d_in[9];
  const float* whh2 = (const float*)d_in[10];
  const float* bih2 = (const float*)d_in[11];
  const float* bhh2 = (const float*)d_in[12];
  const float* ll2w = (const float*)d_in[13];
  const float* ll2b = (const float*)d_in[14];
  const float* lr2w = (const float*)d_in[15];
  const float* linw = (const float*)d_in[16];
  const float* linb = (const float*)d_in[17];

  char* ws = (char*)d_ws;
  u16* xb    = (u16*)(ws);                       // 12,800,000 B
  u16* h1b   = (u16*)(ws + 12800000);            // 12,800,000 B
  u16* wpk1  = (u16*)(ws + 25600000);            //    262,144 B
  u16* wpk2  = (u16*)(ws + 25862144);            //    262,144 B
  u16* epk1  = (u16*)(ws + 26124288);            //     65,536 B
  u16* epk2  = (u16*)(ws + 26189824);            //     65,536 B
  u16* hpk   = (u16*)(ws + 26255360);            //     16,384 B
  float* bs1 = (float*)(ws + 26271744);          //      2,048 B
  float* bs2 = (float*)(ws + 26273792);          //      2,048 B

  k_prep<<<1000, 256, 0, stream>>>(x, xb,
                                   wih1, whh1, wpk1, wih2, whh2, wpk2,
                                   lr1w, ll1w, epk1, lr2w, ll2w, epk2,
                                   linw, hpk,
                                   bih1, bhh1, bs1, bih2, bhh2, bs2);
  k_layer<0><<<NBLK, 1024, 0, stream>>>(xb, edge, wpk1, bs1, epk1, ll1b,
                                        h1b, nullptr, nullptr, nullptr);
  k_layer<1><<<NBLK, 1024, 0, stream>>>(h1b, edge, wpk2, bs2, epk2, ll2b,
                                        nullptr, hpk, linb, (float*)d_out);
}

// Round 9
// 541.628 us; speedup vs baseline: 4.0164x; 4.0164x over previous
//
#include <hip/hip_runtime.h>
#include <stdint.h>

#define NN 50000
#define DEG 16
#define MT 32
#define NBLK ((NN + MT - 1) / MT)
#define LOG2E 1.4426950408889634f

typedef short bf16x8 __attribute__((ext_vector_type(8)));
typedef float f32x4 __attribute__((ext_vector_type(4)));
typedef unsigned short u16;
typedef unsigned int u32;

static __device__ __forceinline__ u16 f2bf(float f) {
  union { float f; u32 u; } v; v.f = f;
  u32 u = v.u + 0x7FFFu + ((v.u >> 16) & 1u);   // round-to-nearest-even
  return (u16)(u >> 16);
}
static __device__ __forceinline__ float rcp_(float x) {
  return __builtin_amdgcn_rcpf(x);
}
static __device__ __forceinline__ float ex2_(float x) {
  return __builtin_amdgcn_exp2f(x);
}
static __device__ __forceinline__ void gload_lds16(const void* g, void* l) {
  __builtin_amdgcn_global_load_lds(
      (const __attribute__((address_space(1))) void*)g,
      (__attribute__((address_space(3))) void*)l, 16, 0, 0);
}

// ---------------------------------------------------------------------------
// Prep. v8 gate-weight layout: 16 waves, wave w owns units u=8w..8w+7, all 4
// gates, packed as 2 ntiles of 16 cols: nt0=[i(u0..7)|f(u0..7)],
// nt1=[g|o]. Col (w,nt,lane): u=8w+(lane&7), G=nt*2+((lane>>3)&1).
// Gates i,f,o are scaled by -log2e (NEGATED: sigmoid needs exp(-x), so the
// negate is folded into the weights, exactly); g by +2*log2e.
//   wpk[(((w*2+nt)*8+kt)*64+lane)*8+j] = sc(G)*W[G*128+u][k],
//   k = kt*32+(lane>>4)*8+j,  W = [w_ih | w_hh] along K.
// ---------------------------------------------------------------------------
__global__ void k_prep(const float* __restrict__ x, u16* __restrict__ xb,
                       const float* __restrict__ wih1, const float* __restrict__ whh1, u16* __restrict__ wpk1,
                       const float* __restrict__ wih2, const float* __restrict__ whh2, u16* __restrict__ wpk2,
                       const float* __restrict__ lr1, const float* __restrict__ ll1, u16* __restrict__ epk1,
                       const float* __restrict__ lr2, const float* __restrict__ ll2, u16* __restrict__ epk2,
                       const float* __restrict__ linw, u16* __restrict__ hpk,
                       const float* __restrict__ bi1, const float* __restrict__ bh1, float* __restrict__ bs1,
                       const float* __restrict__ bi2, const float* __restrict__ bh2, float* __restrict__ bs2) {
  int b = blockIdx.x;
  if (b < 128) {
    const float* wih = (b < 64) ? wih1 : wih2;
    const float* whh = (b < 64) ? whh1 : whh2;
    u16* wpk = (b < 64) ? wpk1 : wpk2;
    int t = (b & 63) * 256 + threadIdx.x;          // 0..16383
    int lane = t & 63, kt = (t >> 6) & 7, nt = (t >> 9) & 1, w = (t >> 10) & 15;
    int u = 8 * w + (lane & 7);
    int G = nt * 2 + ((lane >> 3) & 1);
    int col = G * 128 + u;
    int k0 = kt * 32 + (lane >> 4) * 8;
    float sc = (G == 2) ? 2.f * LOG2E : -LOG2E;
#pragma unroll
    for (int j = 0; j < 8; ++j) {
      int k = k0 + j;
      float v = (k < 128) ? wih[col * 128 + k] : whh[col * 128 + k - 128];
      wpk[t * 8 + j] = f2bf(sc * v);
    }
  } else if (b < 160) {
    // epilogue weights (8-wave layout): k<128 lin_r(x), k>=128 lin_l(h)
    const float* lrw = (b < 144) ? lr1 : lr2;
    const float* llw = (b < 144) ? ll1 : ll2;
    u16* epk = (b < 144) ? epk1 : epk2;
    int t = ((b - 128) & 15) * 256 + threadIdx.x;  // 0..4095
    int lane = t & 63, kt = (t >> 6) & 7, w = (t >> 9) & 7;
    int col = w * 16 + (lane & 15);
    int k0 = kt * 32 + (lane >> 4) * 8;
#pragma unroll
    for (int j = 0; j < 8; ++j) {
      int k = k0 + j;
      epk[t * 8 + j] = f2bf(k < 128 ? lrw[col * 128 + k] : llw[col * 128 + k - 128]);
    }
  } else if (b < 164) {
    // head weights [64,128], waves 0..3 — unscaled
    int t = (b - 160) * 256 + threadIdx.x;         // 0..1023
    int lane = t & 63, kt = (t >> 6) & 3, w = (t >> 8) & 3;
    int col = w * 16 + (lane & 15);
    int k0 = kt * 32 + (lane >> 4) * 8;
#pragma unroll
    for (int j = 0; j < 8; ++j) hpk[t * 8 + j] = f2bf(linw[col * 128 + k0 + j]);
  } else if (b < 168) {
    int t = (b - 164) * 256 + threadIdx.x;         // 0..1023
    if (t < 1024) {
      int i = t & 511;
      float sc = ((i >> 7) == 2) ? 2.f * LOG2E : -LOG2E;
      if (t < 512) bs1[i] = sc * (bi1[i] + bh1[i]);
      else bs2[i] = sc * (bi2[i] + bh2[i]);
    }
  } else {
    int i = (b - 168) * 256 + threadIdx.x;
    int stride = (gridDim.x - 168) * 256;
    for (; i < NN * 128 / 4; i += stride) {
      float4 v = ((const float4*)x)[i];
      ushort4 o;
      o.x = f2bf(v.x); o.y = f2bf(v.y); o.z = f2bf(v.z); o.w = f2bf(v.w);
      ((ushort4*)xb)[i] = o;
    }
  }
}

// ---------------------------------------------------------------------------
// Fused SAGE-LSTM layer, v9 = v8 with CORRECTED launch bounds.
// v8's __launch_bounds__(1024,8) demanded 8 waves/SIMD -> 64-reg cap ->
// compiler spilled the whole weight panel (VGPR_Count 32, WRITE 506MB).
// v9: __launch_bounds__(1024,4) -> 128-reg cap; demand ~115 (wreg 64 + acc 16
// + c 4 + recv 8 + temps) fits. 16 waves/block, 4 waves/SIMD, 1 block/CU:
// 2x v7 occupancy with the halved per-wave EW chain.
// Wave owns 8 hidden units x 4 gates (packed cols); gate exchange in-register
// via __shfl_xor(.,8); i,f,o in NEGATED exp2 domain (bit-exact fold).
// Counted-vmcnt barrier (CBAR) + 2-ahead triple-buffered gather as in v7.
// LDS XOR-swizzle: byte ^= (row&15)<<4.
// ---------------------------------------------------------------------------

#define GATHER(DCODE, PDST)                                                   \
  do {                                                                        \
    int idx_;                                                                 \
    if ((DCODE) < DEG) idx_ = IDX[grow * DEG + (DCODE)];                      \
    else idx_ = (node0 + grow < NN) ? node0 + grow : NN - 1;                  \
    const char* gsw_ = (const char*)(xin + (size_t)idx_ * 128) +              \
                       ((lr * 16) ^ ((grow & 15) << 4));                      \
    gload_lds16(gsw_, (PDST) + ((w & 7) * 4) * 128);                          \
  } while (0)

#define CBAR(N)                                                               \
  do {                                                                        \
    asm volatile("s_waitcnt vmcnt(" #N ") lgkmcnt(0)" ::: "memory");          \
    __builtin_amdgcn_s_barrier();                                             \
    __builtin_amdgcn_sched_barrier(0);                                        \
  } while (0)

template <int L2>
__global__ __launch_bounds__(1024, 4) void k_layer(
    const u16* __restrict__ xin, const int* __restrict__ src,
    const u16* __restrict__ wpk, const float* __restrict__ bsum,
    const u16* __restrict__ epk, const float* __restrict__ linlb,
    u16* __restrict__ hout, const u16* __restrict__ hpk,
    const float* __restrict__ linb, float* __restrict__ dout) {
  __shared__ __align__(16) u16 AX[3][MT * 128];   // 3 x 8 KB (triple buffer)
  __shared__ __align__(16) u16 AH[2][MT * 128];   // 2 x 8 KB
  __shared__ int IDX[MT * DEG];                   // 2 KB

  const int tid = threadIdx.x;
  const int w = tid >> 6, l = tid & 63;
  const int lr = l & 15, lh = l >> 4;
  const int node0 = blockIdx.x * MT;
  const int grow = (w & 7) * 4 + lh;  // gather row (waves 0..7 only)

  // ---- register-resident weight panel: 16 frags = 64 VGPRs ----
  bf16x8 wreg[2][8];
#pragma unroll
  for (int nt = 0; nt < 2; ++nt)
#pragma unroll
    for (int kt = 0; kt < 8; ++kt)
      wreg[nt][kt] = *(const bf16x8*)(wpk + (size_t)(((w * 2 + nt) * 8 + kt) * 64 + l) * 8);

  if (tid < MT * DEG)
    IDX[tid] = (node0 + (tid >> 4) < NN) ? src[node0 * DEG + tid] : 0;

  const int uu = 8 * w + (l & 7);     // this lane's hidden unit
  const bool hi = (l & 8) != 0;       // col>=8 half: owns f,o; rows mt1
  float gb[2];
#pragma unroll
  for (int nt = 0; nt < 2; ++nt)
    gb[nt] = bsum[(nt * 2 + (hi ? 1 : 0)) * 128 + uu];
  __syncthreads();  // IDX ready; vmcnt drained

  // prologue: gather x_0 -> AX[0], x_1 -> AX[1] (waves 0..7)
  if (w < 8) {
    GATHER(0, AX[0]);
    GATHER(1, AX[1]);
  }

  f32x4 c4 = (f32x4){0.f, 0.f, 0.f, 0.f};
  CBAR(1);  // x_0 landed; x_1 still in flight

  u16 *pA = AX[0], *pB = AX[1], *pC = AX[2];

#pragma unroll 1
  for (int step = 0; step < DEG; ++step) {
    const int cb = step & 1, nb = cb ^ 1;

    // issue gather(step+2) into the free buffer (d=16 -> own features)
    if (w < 8 && step < DEG - 1) GATHER(step + 2, pC);

    // acc init = gate bias (pre-scaled/negated): free bias via MFMA C-in
    f32x4 acc[2][2];  // [mt][nt]
#pragma unroll
    for (int mt = 0; mt < 2; ++mt)
#pragma unroll
      for (int nt = 0; nt < 2; ++nt)
        acc[mt][nt] = (f32x4){gb[nt], gb[nt], gb[nt], gb[nt]};

    // x-part: K tiles 0..3
#pragma unroll
    for (int kt = 0; kt < 4; ++kt) {
      bf16x8 af[2];
#pragma unroll
      for (int mt = 0; mt < 2; ++mt) {
        int row = mt * 16 + lr;
        af[mt] = *(const bf16x8*)((const char*)pA + row * 256 +
                                  ((kt * 64 + lh * 16) ^ ((row & 15) << 4)));
      }
#pragma unroll
      for (int nt = 0; nt < 2; ++nt)
#pragma unroll
        for (int mt = 0; mt < 2; ++mt)
          acc[mt][nt] = __builtin_amdgcn_mfma_f32_16x16x32_bf16(af[mt], wreg[nt][kt], acc[mt][nt], 0, 0, 0);
    }

    // h-part: K tiles 4..7 (h == 0 at step 0)
    if (step) {
#pragma unroll
      for (int kt = 0; kt < 4; ++kt) {
        bf16x8 af[2];
#pragma unroll
        for (int mt = 0; mt < 2; ++mt) {
          int row = mt * 16 + lr;
          af[mt] = *(const bf16x8*)((const char*)AH[cb] + row * 256 +
                                    ((kt * 64 + lh * 16) ^ ((row & 15) << 4)));
        }
#pragma unroll
        for (int nt = 0; nt < 2; ++nt)
#pragma unroll
          for (int mt = 0; mt < 2; ++mt)
            acc[mt][nt] = __builtin_amdgcn_mfma_f32_16x16x32_bf16(af[mt], wreg[nt][4 + kt], acc[mt][nt], 0, 0, 0);
      }
    }

    // in-register gate exchange: lane l <-> l^8 (same unit, complementary
    // gates). lo sends its mt1 (i,g), hi sends its mt0 (f,o).
    f32x4 recv[2];
#pragma unroll
    for (int nt = 0; nt < 2; ++nt)
#pragma unroll
      for (int j = 0; j < 4; ++j) {
        float send = hi ? acc[0][nt][j] : acc[1][nt][j];
        recv[nt][j] = __shfl_xor(send, 8, 64);
      }

    // EW: lo lanes do rows mt0, hi lanes rows mt1; 4 elems each, no LDS.
    // i,f,o preacts are NEGATED (sigma(x) = rcp(1+ex2(nx))).
    const int rbase = (hi ? 16 : 0) + lh * 4;
#pragma unroll
    for (int j = 0; j < 4; ++j) {
      float ai = hi ? recv[0][j] : acc[0][0][j];
      float afv = hi ? acc[1][0][j] : recv[0][j];
      float ag = hi ? recv[1][j] : acc[0][1][j];
      float ao = hi ? acc[1][1][j] : recv[1][j];
      float iv = rcp_(1.f + ex2_(ai));
      float fv = rcp_(1.f + ex2_(afv));
      float gv = 1.f - 2.f * rcp_(1.f + ex2_(ag));
      float ov = rcp_(1.f + ex2_(ao));
      float cv = fv * c4[j] + iv * gv;
      c4[j] = cv;
      float th = 1.f - 2.f * rcp_(1.f + ex2_(2.f * LOG2E * cv));
      int row = rbase + j;
      *(u16*)((char*)AH[nb] + row * 256 + ((2 * uu) ^ ((row & 15) << 4))) =
          f2bf(ov * th);
    }

    // counted barrier: drain gather(step+1) only; keep gather(step+2) flying
    if (step < DEG - 1) CBAR(1);
    else CBAR(0);  // last step: drain the own-x gather for the epilogue

    u16* t_ = pA; pA = pB; pB = t_;
    t_ = pB; pB = pC; pC = t_;  // rotate: pA<-pB, pB<-pC, pC<-old pA
  }

  // Epilogue: out = lin_r(x_own) + lin_l(h_final) + b, ReLU. Waves 0..7
  // (v7 layout: wave w' owns out-cols [16w',16w'+16)). pA = own x; AH[0] = h.
  if constexpr (!L2) {
    if (w < 8) {
      float eb = linlb[w * 16 + lr];
      f32x4 eacc[2];
      eacc[0] = (f32x4){eb, eb, eb, eb};
      eacc[1] = (f32x4){eb, eb, eb, eb};
#pragma unroll
      for (int kt = 0; kt < 8; ++kt) {
        const u16* srcb = (kt < 4) ? pA : AH[0];
        int kb = (kt & 3) * 64 + lh * 16;
        bf16x8 af[2];
#pragma unroll
        for (int mt = 0; mt < 2; ++mt) {
          int row = mt * 16 + lr;
          af[mt] = *(const bf16x8*)((const char*)srcb + row * 256 +
                                    (kb ^ ((row & 15) << 4)));
        }
        bf16x8 bf = *(const bf16x8*)(epk + (size_t)((w * 8 + kt) * 64 + l) * 8);
#pragma unroll
        for (int mt = 0; mt < 2; ++mt)
          eacc[mt] = __builtin_amdgcn_mfma_f32_16x16x32_bf16(af[mt], bf, eacc[mt], 0, 0, 0);
      }
#pragma unroll
      for (int mt = 0; mt < 2; ++mt)
#pragma unroll
        for (int r = 0; r < 4; ++r) {
          int node = node0 + mt * 16 + lh * 4 + r;
          if (node < NN) {
            float v = fmaxf(eacc[mt][r], 0.f);
            hout[(size_t)node * 128 + w * 16 + lr] = f2bf(v);
          }
        }
    }
  } else {
    if (w < 8) {
      float eb = linlb[w * 16 + lr];
      f32x4 eacc[2];
      eacc[0] = (f32x4){eb, eb, eb, eb};
      eacc[1] = (f32x4){eb, eb, eb, eb};
#pragma unroll
      for (int kt = 0; kt < 8; ++kt) {
        const u16* srcb = (kt < 4) ? pA : AH[0];
        int kb = (kt & 3) * 64 + lh * 16;
        bf16x8 af[2];
#pragma unroll
        for (int mt = 0; mt < 2; ++mt) {
          int row = mt * 16 + lr;
          af[mt] = *(const bf16x8*)((const char*)srcb + row * 256 +
                                    (kb ^ ((row & 15) << 4)));
        }
        bf16x8 bf = *(const bf16x8*)(epk + (size_t)((w * 8 + kt) * 64 + l) * 8);
#pragma unroll
        for (int mt = 0; mt < 2; ++mt)
          eacc[mt] = __builtin_amdgcn_mfma_f32_16x16x32_bf16(af[mt], bf, eacc[mt], 0, 0, 0);
      }
      // stash relu(h2) into AH[1]
#pragma unroll
      for (int mt = 0; mt < 2; ++mt)
#pragma unroll
        for (int r = 0; r < 4; ++r) {
          int row = mt * 16 + lh * 4 + r;
          float v = fmaxf(eacc[mt][r], 0.f);
          int jj = 2 * (w * 16 + lr);
          *(u16*)((char*)AH[1] + row * 256 + (jj ^ ((row & 15) << 4))) = f2bf(v);
        }
    }
    __syncthreads();
    if (w < 4) {
      float hb = linb[w * 16 + lr];
      f32x4 hacc[2];
      hacc[0] = (f32x4){hb, hb, hb, hb};
      hacc[1] = (f32x4){hb, hb, hb, hb};
#pragma unroll
      for (int kt = 0; kt < 4; ++kt) {
        bf16x8 af[2];
#pragma unroll
        for (int mt = 0; mt < 2; ++mt) {
          int row = mt * 16 + lr;
          af[mt] = *(const bf16x8*)((const char*)AH[1] + row * 256 +
                                    ((kt * 64 + lh * 16) ^ ((row & 15) << 4)));
        }
        bf16x8 bf = *(const bf16x8*)(hpk + (size_t)((w * 4 + kt) * 64 + l) * 8);
#pragma unroll
        for (int mt = 0; mt < 2; ++mt)
          hacc[mt] = __builtin_amdgcn_mfma_f32_16x16x32_bf16(af[mt], bf, hacc[mt], 0, 0, 0);
      }
#pragma unroll
      for (int mt = 0; mt < 2; ++mt)
#pragma unroll
        for (int r = 0; r < 4; ++r) {
          int node = node0 + mt * 16 + lh * 4 + r;
          if (node < NN) dout[(size_t)node * 64 + w * 16 + lr] = hacc[mt][r];
        }
    }
  }
}

extern "C" void kernel_launch(void* const* d_in, const int* in_sizes, int n_in,
                              void* d_out, int out_size, void* d_ws, size_t ws_size,
                              hipStream_t stream) {
  const float* x    = (const float*)d_in[0];
  const int*   edge = (const int*)d_in[1];   // src = first N*DEG entries
  const float* wih1 = (const float*)d_in[2];
  const float* whh1 = (const float*)d_in[3];
  const float* bih1 = (const float*)d_in[4];
  const float* bhh1 = (const float*)d_in[5];
  const float* ll1w = (const float*)d_in[6];
  const float* ll1b = (const float*)d_in[7];
  const float* lr1w = (const float*)d_in[8];
  const float* wih2 = (const float*)d_in[9];
  const float* whh2 = (const float*)d_in[10];
  const float* bih2 = (const float*)d_in[11];
  const float* bhh2 = (const float*)d_in[12];
  const float* ll2w = (const float*)d_in[13];
  const float* ll2b = (const float*)d_in[14];
  const float* lr2w = (const float*)d_in[15];
  const float* linw = (const float*)d_in[16];
  const float* linb = (const float*)d_in[17];

  char* ws = (char*)d_ws;
  u16* xb    = (u16*)(ws);                       // 12,800,000 B
  u16* h1b   = (u16*)(ws + 12800000);            // 12,800,000 B
  u16* wpk1  = (u16*)(ws + 25600000);            //    262,144 B
  u16* wpk2  = (u16*)(ws + 25862144);            //    262,144 B
  u16* epk1  = (u16*)(ws + 26124288);            //     65,536 B
  u16* epk2  = (u16*)(ws + 26189824);            //     65,536 B
  u16* hpk   = (u16*)(ws + 26255360);            //     16,384 B
  float* bs1 = (float*)(ws + 26271744);          //      2,048 B
  float* bs2 = (float*)(ws + 26273792);          //      2,048 B

  k_prep<<<1000, 256, 0, stream>>>(x, xb,
                                   wih1, whh1, wpk1, wih2, whh2, wpk2,
                                   lr1w, ll1w, epk1, lr2w, ll2w, epk2,
                                   linw, hpk,
                                   bih1, bhh1, bs1, bih2, bhh2, bs2);
  k_layer<0><<<NBLK, 1024, 0, stream>>>(xb, edge, wpk1, bs1, epk1, ll1b,
                                        h1b, nullptr, nullptr, nullptr);
  k_layer<1><<<NBLK, 1024, 0, stream>>>(h1b, edge, wpk2, bs2, epk2, ll2b,
                                        nullptr, hpk, linb, (float*)d_out);
}